// Round 2
// baseline (380.723 us; speedup 1.0000x reference)
//
#include <hip/hip_runtime.h>
#include <hip/hip_bf16.h>

#define B_ 64
#define T_ 4096
#define DQ_ 512
#define DF_ 256
#define H_ 8
#define D_ 64
#define EPS_ 1e-7f
#define TCH 64          /* rows per chunk */
#define CPB 16          /* chunks per block (persistent) */
#define NBLK 256        /* blocks = CUs; 4 blocks per batch b */
#define PSZ 66          /* per-(block,h) partial: m, l, out[64] */

typedef __attribute__((ext_vector_type(8))) short short8;
typedef __attribute__((ext_vector_type(4))) float f32x4;

static __device__ __forceinline__ unsigned short f2bf(float f) {
  union { float f; unsigned int u; } x; x.f = f;
  unsigned int u = x.u;
  unsigned int r = (u + 0x7fffu + ((u >> 16) & 1u)) >> 16; // RNE
  return (unsigned short)r;
}

static __device__ __forceinline__ unsigned int pk2(float a, float b) {
  __hip_bfloat162 h = __float22bfloat162_rn(make_float2(a, b));
  union { __hip_bfloat162 h; unsigned int u; } c; c.h = h;
  return c.u;
}

// fq[b,h,d] = sum_f query[b,f] * Wq[h,f,d] + bq[h,d]   (fp32)
__global__ void prep_fq(const float* __restrict__ q, const float* __restrict__ Wq,
                        const float* __restrict__ bq, float* __restrict__ fq) {
  int bh = blockIdx.x;
  int b = bh >> 3, h = bh & 7;
  int d = threadIdx.x;
  const float* qb = q + (size_t)b * DQ_;
  const float* w = Wq + (size_t)h * DQ_ * D_ + d;
  float acc = bq[h * D_ + d];
#pragma unroll 8
  for (int f = 0; f < DQ_; ++f) acc += qb[f] * w[(size_t)f * D_];
  fq[bh * D_ + d] = acc;
}

// WfT[h][d][k] = bf16(Wf[h][k][d])
__global__ void prep_wft(const float* __restrict__ Wf, unsigned short* __restrict__ WfT) {
  int hd = blockIdx.x; // h*64 + d
  int h = hd >> 6, d = hd & 63;
  int t = threadIdx.x; // 64 threads
  const float* src = Wf + (size_t)h * DF_ * D_ + d;
  unsigned short* dst = WfT + (size_t)hd * DF_;
#pragma unroll
  for (int i = 0; i < 4; ++i) {
    int k = i * 64 + t;
    dst[k] = f2bf(src[(size_t)k * D_]);
  }
}

// Persistent main kernel: 256 blocks, 8 waves = 8 heads, 16 chunks of 64 rows.
// Online softmax state carried across all chunks; one partial store per block.
__global__ __launch_bounds__(512, 2) void mha_main(
    const float* __restrict__ fact, const float* __restrict__ fq_ws,
    const unsigned short* __restrict__ WfT,
    float* __restrict__ part, float* __restrict__ cspart) {
  __shared__ unsigned short lds[2][TCH * DF_]; // 2 x 32 KB bf16 tiles

  const int bid = blockIdx.x;
  const int tid = threadIdx.x;
  const int l = tid & 63, w = tid >> 6; // wave == head
  const int dl = l & 15, kg = l >> 4;

  const int c0 = bid * CPB;
  const int b = c0 >> 6;       // 64 chunks per batch
  const int tc0 = c0 & 63;

  // A-fragments: this head's Wf^T rows (d x k), held in registers
  short8 bfrag[4][8];
  {
    const unsigned short* wb = WfT + (size_t)w * D_ * DF_;
#pragma unroll
    for (int n = 0; n < 4; ++n)
#pragma unroll
      for (int ks = 0; ks < 8; ++ks)
        bfrag[n][ks] = *(const short8*)(wb + (n * 16 + dl) * DF_ + ks * 32 + kg * 8);
  }
  // per-lane fq values at d = n*16 + kg*4 + r
  float fqr_s[16];
#pragma unroll
  for (int n = 0; n < 4; ++n)
#pragma unroll
    for (int r = 0; r < 4; ++r)
      fqr_s[n * 4 + r] = fq_ws[(b * 8 + w) * D_ + n * 16 + kg * 4 + r];

  const float* factb = fact + (size_t)b * T_ * DF_;

  // prologue: issue chunk-0 loads (one full 1KB row per wave-instruction)
  float4 pre[8];
#pragma unroll
  for (int g = 0; g < 4; ++g) {
    pre[2 * g]     = *(const float4*)(factb + (size_t)(tc0 * TCH + g * 16 + w) * DF_ + l * 4);
    pre[2 * g + 1] = *(const float4*)(factb + (size_t)(tc0 * TCH + g * 16 + 8 + w) * DF_ + l * 4);
  }

  float m_run = -INFINITY, l_part = 0.f;
  float out_p[16], cs_p[16];
#pragma unroll
  for (int j = 0; j < 16; ++j) { out_p[j] = 0.f; cs_p[j] = 0.f; }

  const int wswz = w << 4;
  for (int i = 0; i < CPB; ++i) {
    char* buf = (char*)lds + (i & 1) * 32768;
    // convert chunk i (waits on its loads) and write to LDS, XOR-swizzled
#pragma unroll
    for (int g = 0; g < 4; ++g) {
      float4 v0 = pre[2 * g], v1 = pre[2 * g + 1];
      int r0 = g * 16 + w, r1 = g * 16 + 8 + w;
      uint2 u0, u1;
      u0.x = pk2(v0.x, v0.y); u0.y = pk2(v0.z, v0.w);
      u1.x = pk2(v1.x, v1.y); u1.y = pk2(v1.z, v1.w);
      *(uint2*)(buf + ((r0 * 512 + l * 8) ^ wswz)) = u0;
      *(uint2*)(buf + ((r1 * 512 + l * 8) ^ wswz)) = u1;
    }
    __syncthreads(); // only barrier per chunk; no vmem outstanding here

    // issue next chunk's loads AFTER the barrier -> they stream under compute
    if (i + 1 < CPB) {
      int tcn = tc0 + i + 1;
#pragma unroll
      for (int g = 0; g < 4; ++g) {
        pre[2 * g]     = *(const float4*)(factb + (size_t)(tcn * TCH + g * 16 + w) * DF_ + l * 4);
        pre[2 * g + 1] = *(const float4*)(factb + (size_t)(tcn * TCH + g * 16 + 8 + w) * DF_ + l * 4);
      }
    }

    // compute 4 row-groups of this chunk; D: col(lane&15)=t, row(kg*4+r)=d
#pragma unroll
    for (int g = 0; g < 4; ++g) {
      f32x4 acc[4];
#pragma unroll
      for (int n = 0; n < 4; ++n) { f32x4 z = {0.f, 0.f, 0.f, 0.f}; acc[n] = z; }
      const int abase = (g * 16 + dl) * 512;
      const int aswz = (dl & 7) << 4;
#pragma unroll
      for (int ks = 0; ks < 8; ++ks) {
        short8 fr = *(const short8*)(buf + ((abase + ks * 64 + kg * 16) ^ aswz));
#pragma unroll
        for (int n = 0; n < 4; ++n)
          acc[n] = __builtin_amdgcn_mfma_f32_16x16x32_bf16(bfrag[n][ks], fr, acc[n], 0, 0, 0);
      }
      // dot over d: 16 in-lane FMAs + combine the 4 kg-groups
      float pp = 0.f;
#pragma unroll
      for (int n = 0; n < 4; ++n)
#pragma unroll
        for (int r = 0; r < 4; ++r) pp += acc[n][r] * fqr_s[n * 4 + r];
      pp += __shfl_xor(pp, 16);
      pp += __shfl_xor(pp, 32);
      // tile max over the 16 t's
      float mt = pp;
      mt = fmaxf(mt, __shfl_xor(mt, 1));
      mt = fmaxf(mt, __shfl_xor(mt, 2));
      mt = fmaxf(mt, __shfl_xor(mt, 4));
      mt = fmaxf(mt, __shfl_xor(mt, 8));
      if (mt > m_run + 8.f) { // defer-max: rescale only on significant growth
        float sc = __expf(m_run - mt);
#pragma unroll
        for (int j = 0; j < 16; ++j) out_p[j] *= sc;
        l_part *= sc;
        m_run = mt;
      }
      float wgt = __expf(pp - m_run);
      l_part += wgt;
#pragma unroll
      for (int n = 0; n < 4; ++n)
#pragma unroll
        for (int r = 0; r < 4; ++r) {
          out_p[n * 4 + r] += wgt * acc[n][r];
          cs_p[n * 4 + r] += acc[n][r];
        }
    }
  }

  // block epilogue: reduce over the 16 t-lanes (within kg group), store partials
#pragma unroll
  for (int j = 0; j < 16; ++j) {
    out_p[j] += __shfl_xor(out_p[j], 1);
    out_p[j] += __shfl_xor(out_p[j], 2);
    out_p[j] += __shfl_xor(out_p[j], 4);
    out_p[j] += __shfl_xor(out_p[j], 8);
    cs_p[j] += __shfl_xor(cs_p[j], 1);
    cs_p[j] += __shfl_xor(cs_p[j], 2);
    cs_p[j] += __shfl_xor(cs_p[j], 4);
    cs_p[j] += __shfl_xor(cs_p[j], 8);
  }
  l_part += __shfl_xor(l_part, 1);
  l_part += __shfl_xor(l_part, 2);
  l_part += __shfl_xor(l_part, 4);
  l_part += __shfl_xor(l_part, 8);

  float* pb = part + ((size_t)bid * 8 + w) * PSZ;
  float* cb = cspart + ((size_t)bid * 8 + w) * D_;
  if (l == 0) { pb[0] = m_run; pb[1] = l_part; }
  if (dl == 0) {
#pragma unroll
    for (int n = 0; n < 4; ++n)
#pragma unroll
      for (int r = 0; r < 4; ++r) {
        pb[2 + n * 16 + kg * 4 + r] = out_p[n * 4 + r];
        cb[n * 16 + kg * 4 + r] = cs_p[n * 4 + r];
      }
  }
}

// combine the 4 block-partials per (b,h); add bias + EPS*colsum terms
__global__ void reduce_k(const float* __restrict__ part, const float* __restrict__ cspart,
                         const float* __restrict__ bf, float* __restrict__ out) {
  int bh = blockIdx.x; // b*8+h
  int b = bh >> 3, h = bh & 7;
  int d = threadIdx.x;
  float M = -INFINITY;
  float mj[4];
#pragma unroll
  for (int j = 0; j < 4; ++j) {
    mj[j] = part[(((size_t)(b * 4 + j)) * 8 + h) * PSZ];
    M = fmaxf(M, mj[j]);
  }
  float L = 0.f, acc = 0.f, cs = 0.f;
#pragma unroll
  for (int j = 0; j < 4; ++j) {
    const float* pj = part + (((size_t)(b * 4 + j)) * 8 + h) * PSZ;
    float e = __expf(mj[j] - M);
    L += e * pj[1];
    acc += e * pj[2 + d];
    cs += cspart[(((size_t)(b * 4 + j)) * 8 + h) * D_ + d];
  }
  float bv = bf[h * D_ + d];
  out[(size_t)b * (H_ * D_) + h * D_ + d] = acc / L + bv + EPS_ * (cs + (float)T_ * bv);
}

extern "C" void kernel_launch(void* const* d_in, const int* in_sizes, int n_in,
                              void* d_out, int out_size, void* d_ws, size_t ws_size,
                              hipStream_t stream) {
  const float* query = (const float*)d_in[0];
  const float* fact  = (const float*)d_in[1];
  const float* Wq    = (const float*)d_in[2];
  const float* bq    = (const float*)d_in[3];
  const float* Wf    = (const float*)d_in[4];
  const float* bf    = (const float*)d_in[5];
  float* out = (float*)d_out;

  char* ws = (char*)d_ws;
  float* fq = (float*)ws;                                 // 131072 B
  unsigned short* WfT = (unsigned short*)(ws + 131072);   // 262144 B
  float* part = (float*)(ws + 393216);                    // 256*8*66*4 = 540672 B
  float* cspart = (float*)(ws + 933888);                  // 256*8*64*4 = 524288 B

  prep_fq<<<dim3(B_ * H_), dim3(64), 0, stream>>>(query, Wq, bq, fq);
  prep_wft<<<dim3(H_ * D_), dim3(64), 0, stream>>>(Wf, WfT);
  mha_main<<<dim3(NBLK), dim3(512), 0, stream>>>(fact, fq, WfT, part, cspart);
  reduce_k<<<dim3(B_ * H_), dim3(64), 0, stream>>>(part, cspart, bf, out);
}

// Round 3
// 152.379 us; speedup vs baseline: 2.4985x; 2.4985x over previous
//
#include <hip/hip_runtime.h>
#include <hip/hip_bf16.h>

#define B_ 64
#define T_ 4096
#define DQ_ 512
#define DF_ 256
#define H_ 8
#define D_ 64
#define EPS_ 1e-7f
#define WPB 16          /* waves per batch b */
#define TPW (T_ / WPB)  /* 256 t-rows per wave */
#define NWAVE (B_ * WPB) /* 1024 */
#define PS_STRIDE 2304  /* per-wave partial: 9 rows x 256 dims */

typedef __attribute__((ext_vector_type(8))) short short8;
typedef __attribute__((ext_vector_type(4))) float f32x4;

union U8 { uint4 u; short8 s; };

static __device__ __forceinline__ unsigned int pk2(float a, float b) {
  __hip_bfloat162 h = __float22bfloat162_rn(make_float2(a, b));
  union { __hip_bfloat162 h; unsigned int u; } c; c.h = h;
  return c.u;
}

// fq[b,h,d] = query[b]@Wq[h] + bq[h]
__global__ void prep_fq(const float* __restrict__ q, const float* __restrict__ Wq,
                        const float* __restrict__ bq, float* __restrict__ fq) {
  int bh = blockIdx.x;
  int b = bh >> 3, h = bh & 7;
  int d = threadIdx.x;
  const float* qb = q + (size_t)b * DQ_;
  const float* w = Wq + (size_t)h * DQ_ * D_ + d;
  float acc = bq[h * D_ + d];
#pragma unroll 8
  for (int f = 0; f < DQ_; ++f) acc += qb[f] * w[(size_t)f * D_];
  fq[bh * D_ + d] = acc;
}

// v[b,h,k] = Wf[h,k,:]·fq[b,h,:]; packed as vB[b][ks][lane][j] bf16 for B-fragments
// (lane = kg*16 + dl; element = v[ks*32 + kg*8 + j][h=dl], zero for dl>=8)
__global__ void prep_v(const float* __restrict__ Wf, const float* __restrict__ fq,
                       unsigned short* __restrict__ vB) {
  __shared__ float fql[D_];
  int bh = blockIdx.x;
  int b = bh >> 3, h = bh & 7;
  int k = threadIdx.x; // 256 threads
  if (k < D_) fql[k] = fq[bh * D_ + k];
  __syncthreads();
  const float* wrow = Wf + (size_t)h * DF_ * D_ + (size_t)k * D_;
  float acc = 0.f;
#pragma unroll 8
  for (int d = 0; d < D_; ++d) acc += wrow[d] * fql[d];
  int ks = k >> 5, kg = (k >> 3) & 3, j = k & 7;
  size_t base = (size_t)b * 4096 + ks * 512;
  // value slot at dl = h
  vB[base + (kg * 16 + h) * 8 + j] = (unsigned short)(pk2(acc, 0.f) & 0xFFFF);
  // zero slot at dl = 8 + h
  vB[base + (kg * 16 + 8 + h) * 8 + j] = 0;
}

// Main: 256 WGs x 256 thr = 1024 independent waves; wave handles all 8 heads
// for its 256-row t-slice. No LDS, no barriers.
__global__ __launch_bounds__(256, 1) void mha_main(
    const float* __restrict__ fact, const unsigned short* __restrict__ vB,
    float* __restrict__ part_s, float* __restrict__ part_ml) {
  const int tid = threadIdx.x;
  const int l = tid & 63;
  const int dl = l & 15, kg = l >> 4;
  const int gwave = blockIdx.x * 4 + (tid >> 6);
  const int b = gwave >> 4;
  const int wseq = gwave & 15;
  const int t_base = wseq * TPW;

  // v B-fragments (all 8 heads): 8 k-steps x short8
  short8 vfrag[8];
#pragma unroll
  for (int ks = 0; ks < 8; ++ks)
    vfrag[ks] = *(const short8*)(vB + (size_t)b * 4096 + ks * 512 + l * 8);

  const float* factb = fact + (size_t)b * T_ * DF_;

  // A-load macro target buffers (fp32, 16 float4 each = one 16-row tile's lane share)
  float4 AF0[16], AF1[16];
  const float* arow_base = factb + (size_t)(t_base + dl) * DF_ + kg * 8;

#define LOADA(BUF, TILE)                                                       \
  {                                                                            \
    const float* ar = arow_base + (size_t)(TILE) * 16 * DF_;                   \
    _Pragma("unroll") for (int ks = 0; ks < 8; ++ks) {                         \
      BUF[2 * ks] = *(const float4*)(ar + ks * 32);                            \
      BUF[2 * ks + 1] = *(const float4*)(ar + ks * 32 + 4);                    \
    }                                                                          \
  }

#define LOGITS(BUF, DST)                                                       \
  {                                                                            \
    f32x4 dacc = {0.f, 0.f, 0.f, 0.f};                                         \
    _Pragma("unroll") for (int ks = 0; ks < 8; ++ks) {                         \
      U8 a;                                                                    \
      a.u.x = pk2(BUF[2 * ks].x, BUF[2 * ks].y);                               \
      a.u.y = pk2(BUF[2 * ks].z, BUF[2 * ks].w);                               \
      a.u.z = pk2(BUF[2 * ks + 1].x, BUF[2 * ks + 1].y);                       \
      a.u.w = pk2(BUF[2 * ks + 1].z, BUF[2 * ks + 1].w);                       \
      dacc = __builtin_amdgcn_mfma_f32_16x16x32_bf16(a.s, vfrag[ks], dacc, 0, 0, 0); \
    }                                                                          \
    DST = dacc;                                                                \
  }

  // scatter row pointers for the S-MFMA B-operand (8 t-rows per lane)
  const float* rp[8];
#pragma unroll
  for (int j = 0; j < 8; ++j)
    rp[j] = factb + (size_t)(t_base + kg * 8 + j) * DF_ + dl;

  float m_run = -INFINITY, l_part = 0.f;
  f32x4 acc_s[16];
#pragma unroll
  for (int n = 0; n < 16; ++n) { f32x4 z = {0.f, 0.f, 0.f, 0.f}; acc_s[n] = z; }

  LOADA(AF0, 0);
  LOADA(AF1, 1);

  for (int p = 0; p < 8; ++p) {
    f32x4 l0, l1;
    LOGITS(AF0, l0);
    if (p < 7) LOADA(AF0, 2 * p + 2);
    LOGITS(AF1, l1);
    if (p < 7) LOADA(AF1, 2 * p + 3);

    // ---- online softmax over the 32-t pair ----
    float tmax = fmaxf(fmaxf(fmaxf(l0.x, l0.y), fmaxf(l0.z, l0.w)),
                       fmaxf(fmaxf(l1.x, l1.y), fmaxf(l1.z, l1.w)));
    tmax = fmaxf(tmax, __shfl_xor(tmax, 16));
    tmax = fmaxf(tmax, __shfl_xor(tmax, 32));
    int need = (tmax > m_run + 8.f) && (dl < 8);
    if (__any(need)) {
      float mnew = fmaxf(m_run, tmax);
      float f = __expf(m_run - mnew);
      m_run = mnew;
      l_part *= f;
      float f0 = __shfl(f, kg * 4 + 0);
      float f1 = __shfl(f, kg * 4 + 1);
      float f2 = __shfl(f, kg * 4 + 2);
      float f3 = __shfl(f, kg * 4 + 3);
      if (kg < 2) {
#pragma unroll
        for (int n = 0; n < 16; ++n) {
          acc_s[n].x *= f0; acc_s[n].y *= f1; acc_s[n].z *= f2; acc_s[n].w *= f3;
        }
      }
    }
    float e00 = __expf(l0.x - m_run), e01 = __expf(l0.y - m_run);
    float e02 = __expf(l0.z - m_run), e03 = __expf(l0.w - m_run);
    float e10 = __expf(l1.x - m_run), e11 = __expf(l1.y - m_run);
    float e12 = __expf(l1.z - m_run), e13 = __expf(l1.w - m_run);
    l_part += (e00 + e01 + e02 + e03) + (e10 + e11 + e12 + e13);

    unsigned int pk00 = pk2(e00, e01), pk01 = pk2(e02, e03);
    unsigned int pk10 = pk2(e10, e11), pk11 = pk2(e12, e13);
    if (dl == 8) { pk00 = pk01 = pk10 = pk11 = 0x3F803F80u; } // ones row -> colsum

    // gather e^T A-fragment from logits D-layout (8 bpermutes + 4 selects)
    int sa = dl + ((kg & 1) ? 32 : 0);
    int sb = sa + 16;
    unsigned int g00 = __shfl(pk00, sa), g01 = __shfl(pk01, sa);
    unsigned int g02 = __shfl(pk00, sb), g03 = __shfl(pk01, sb);
    unsigned int g10 = __shfl(pk10, sa), g11 = __shfl(pk11, sa);
    unsigned int g12 = __shfl(pk10, sb), g13 = __shfl(pk11, sb);
    U8 eA;
    eA.u.x = (kg < 2) ? g00 : g10;
    eA.u.y = (kg < 2) ? g01 : g11;
    eA.u.z = (kg < 2) ? g02 : g12;
    eA.u.w = (kg < 2) ? g03 : g13;

    // ---- S += e^T @ fact  (B from transposed scatter reads, L2-resident) ----
#pragma unroll
    for (int n = 0; n < 16; ++n) {
      float b0 = rp[0][n * 16], b1 = rp[1][n * 16], b2 = rp[2][n * 16], b3 = rp[3][n * 16];
      float b4 = rp[4][n * 16], b5 = rp[5][n * 16], b6 = rp[6][n * 16], b7 = rp[7][n * 16];
      U8 bf;
      bf.u.x = pk2(b0, b1); bf.u.y = pk2(b2, b3);
      bf.u.z = pk2(b4, b5); bf.u.w = pk2(b6, b7);
      acc_s[n] = __builtin_amdgcn_mfma_f32_16x16x32_bf16(eA.s, bf.s, acc_s[n], 0, 0, 0);
    }
#pragma unroll
    for (int j = 0; j < 8; ++j) rp[j] += 32 * DF_;
  }

  // ---- epilogue: store per-wave partials ----
  l_part += __shfl_xor(l_part, 16);
  l_part += __shfl_xor(l_part, 32);
  if (l < 8) {
    part_ml[(size_t)gwave * 16 + l] = m_run;
    part_ml[(size_t)gwave * 16 + 8 + l] = l_part;
  }
  float* ps = part_s + (size_t)gwave * PS_STRIDE;
  if (kg < 2) {
#pragma unroll
    for (int n = 0; n < 16; ++n) {
      ps[(kg * 4 + 0) * 256 + n * 16 + dl] = acc_s[n].x;
      ps[(kg * 4 + 1) * 256 + n * 16 + dl] = acc_s[n].y;
      ps[(kg * 4 + 2) * 256 + n * 16 + dl] = acc_s[n].z;
      ps[(kg * 4 + 3) * 256 + n * 16 + dl] = acc_s[n].w;
    }
  } else if (kg == 2) {
#pragma unroll
    for (int n = 0; n < 16; ++n)
      ps[8 * 256 + n * 16 + dl] = acc_s[n].x; // colsum row
  }
}

// combine wave partials; project s through Wf[h]; add bias terms
__global__ void reduce_k(const float* __restrict__ part_s, const float* __restrict__ part_ml,
                         const float* __restrict__ Wf, const float* __restrict__ bf,
                         float* __restrict__ out) {
  __shared__ float s_l[DF_];
  int bh = blockIdx.x; // b*8+h
  int b = bh >> 3, h = bh & 7;
  int tid = threadIdx.x; // 64 threads

  float M = -INFINITY;
#pragma unroll 4
  for (int w = 0; w < WPB; ++w)
    M = fmaxf(M, part_ml[(size_t)(b * WPB + w) * 16 + h]);

  float Ls = 0.f;
  float sa0 = 0.f, sa1 = 0.f, sa2 = 0.f, sa3 = 0.f;
  float cs0 = 0.f, cs1 = 0.f, cs2 = 0.f, cs3 = 0.f;
#pragma unroll 4
  for (int w = 0; w < WPB; ++w) {
    const float* ml = part_ml + (size_t)(b * WPB + w) * 16;
    float ew = __expf(ml[h] - M);
    Ls += ew * ml[8 + h];
    const float* ps = part_s + (size_t)(b * WPB + w) * PS_STRIDE;
    const float* sr = ps + h * 256 + tid;
    const float* cr = ps + 8 * 256 + tid;
    sa0 += ew * sr[0];   sa1 += ew * sr[64];
    sa2 += ew * sr[128]; sa3 += ew * sr[192];
    cs0 += cr[0];   cs1 += cr[64];
    cs2 += cr[128]; cs3 += cr[192];
  }
  float inv = 1.f / Ls;
  s_l[tid]       = sa0 * inv + EPS_ * cs0;
  s_l[tid + 64]  = sa1 * inv + EPS_ * cs1;
  s_l[tid + 128] = sa2 * inv + EPS_ * cs2;
  s_l[tid + 192] = sa3 * inv + EPS_ * cs3;
  __syncthreads();

  const float* wcol = Wf + (size_t)h * DF_ * D_ + tid;
  float o = 0.f;
#pragma unroll 8
  for (int k = 0; k < DF_; ++k) o += s_l[k] * wcol[(size_t)k * D_];
  o += (1.f + (float)T_ * EPS_) * bf[h * D_ + tid];
  out[(size_t)b * (H_ * D_) + h * D_ + tid] = o;
}

extern "C" void kernel_launch(void* const* d_in, const int* in_sizes, int n_in,
                              void* d_out, int out_size, void* d_ws, size_t ws_size,
                              hipStream_t stream) {
  const float* query = (const float*)d_in[0];
  const float* fact  = (const float*)d_in[1];
  const float* Wq    = (const float*)d_in[2];
  const float* bq    = (const float*)d_in[3];
  const float* Wf    = (const float*)d_in[4];
  const float* bf    = (const float*)d_in[5];
  float* out = (float*)d_out;

  char* ws = (char*)d_ws;
  float* fq = (float*)ws;                                  // 131072 B
  unsigned short* vB = (unsigned short*)(ws + 131072);     // 524288 B
  float* part_ml = (float*)(ws + 655360);                  // 65536 B
  float* part_s = (float*)(ws + 720896);                   // 9437184 B

  prep_fq<<<dim3(B_ * H_), dim3(64), 0, stream>>>(query, Wq, bq, fq);
  prep_v<<<dim3(B_ * H_), dim3(256), 0, stream>>>(Wf, fq, vB);
  mha_main<<<dim3(NWAVE / 4), dim3(256), 0, stream>>>(fact, vB, part_s, part_ml);
  reduce_k<<<dim3(B_ * H_), dim3(64), 0, stream>>>(part_s, part_ml, Wf, bf, out);
}

// Round 4
// 142.081 us; speedup vs baseline: 2.6796x; 1.0725x over previous
//
#include <hip/hip_runtime.h>
#include <hip/hip_bf16.h>

#define B_ 64
#define T_ 4096
#define DQ_ 512
#define DF_ 256
#define H_ 8
#define D_ 64
#define EPS_ 1e-7f
#define NBLK 512        /* (b, q): 8 blocks per batch */
#define TPW 128         /* t-rows per wave */
#define PS_STRIDE 2304  /* per-block partial: 9 rows x 256 */

typedef __attribute__((ext_vector_type(8))) short short8;
typedef __attribute__((ext_vector_type(4))) float f32x4;

union U8 { uint4 u; short8 s; };

static __device__ __forceinline__ unsigned int pk2(float a, float b) {
  __hip_bfloat162 h = __float22bfloat162_rn(make_float2(a, b));
  union { __hip_bfloat162 h; unsigned int u; } c; c.h = h;
  return c.u;
}

// fq[b,h,:] = q[b]@Wq[h] + bq[h]; 4-way f-split, LDS-staged q
__global__ __launch_bounds__(256) void prep_fq(const float* __restrict__ qin,
    const float* __restrict__ Wq, const float* __restrict__ bq,
    float* __restrict__ fq) {
  __shared__ float qs[DQ_];
  __shared__ float red[4][D_];
  int bh = blockIdx.x, b = bh >> 3, h = bh & 7;
  int tid = threadIdx.x, d = tid & 63, fc = tid >> 6;
  qs[tid] = qin[(size_t)b * DQ_ + tid];
  qs[tid + 256] = qin[(size_t)b * DQ_ + tid + 256];
  __syncthreads();
  const float* w = Wq + (size_t)h * DQ_ * D_ + (size_t)fc * 128 * D_ + d;
  float acc = 0.f;
#pragma unroll 8
  for (int i = 0; i < 128; ++i) acc += qs[fc * 128 + i] * w[(size_t)i * D_];
  red[fc][d] = acc;
  __syncthreads();
  if (fc == 0)
    fq[(size_t)bh * D_ + d] = acc + red[1][d] + red[2][d] + red[3][d] + bq[h * D_ + d];
}

// v[b,h,k] = Wf[h,k,:]·fq[b,h,:], packed bf16 B-fragments (zeros at dl=8+h)
__global__ __launch_bounds__(256) void prep_v(const float* __restrict__ Wf,
    const float* __restrict__ fq, unsigned short* __restrict__ vB) {
  __shared__ float fql[D_];
  int bh = blockIdx.x, b = bh >> 3, h = bh & 7;
  int k = threadIdx.x;
  if (k < D_) fql[k] = fq[(size_t)bh * D_ + k];
  __syncthreads();
  const float4* wr = (const float4*)(Wf + (size_t)h * DF_ * D_ + (size_t)k * D_);
  const float4* f4 = (const float4*)fql;
  float acc = 0.f;
#pragma unroll
  for (int i = 0; i < 16; ++i) {
    float4 wv = wr[i], fv = f4[i];
    acc += wv.x * fv.x + wv.y * fv.y + wv.z * fv.z + wv.w * fv.w;
  }
  int ks = k >> 5, kg = (k >> 3) & 3, j = k & 7;
  size_t base = (size_t)b * 4096 + ks * 512;
  vB[base + (kg * 16 + h) * 8 + j] = (unsigned short)(pk2(acc, 0.f) & 0xFFFF);
  vB[base + (kg * 16 + 8 + h) * 8 + j] = 0;
}

// Main: 512 blocks x 4 waves; wave = 128-row t-slice; block merges 4 waves in LDS.
__global__ __launch_bounds__(256, 2) void mha_main(
    const float* __restrict__ fact, const unsigned short* __restrict__ vB,
    float* __restrict__ part_s, float* __restrict__ part_ml) {
  __shared__ float smS[4][9][256];  // 36 KB
  __shared__ float smML[4][2][8];

  const int tid = threadIdx.x;
  const int l = tid & 63, w = tid >> 6;
  const int dl = l & 15, kg = l >> 4;
  const int bid = blockIdx.x;
  const int b = bid >> 3, qq = bid & 7;
  const int t_base = (qq * 4 + w) * TPW;

  short8 vfrag[8];
#pragma unroll
  for (int ks = 0; ks < 8; ++ks)
    vfrag[ks] = *(const short8*)(vB + (size_t)b * 4096 + ks * 512 + l * 8);

  const float* factb = fact + (size_t)b * T_ * DF_;
  const float* ar = factb + (size_t)(t_base + dl) * DF_ + kg * 8;
  const float* rpA = factb + (size_t)(t_base + kg * 8) * DF_ + dl;
  const float* rpB = rpA + 4 * DF_;

  float4 rw[16];   // raw fp32 staging for one 16-row tile
  U8 af0[8], af1[8];

#define ISSUE(T)                                                              \
  { const float* p_ = ar + (size_t)(T) * 16 * DF_;                            \
    _Pragma("unroll") for (int ks = 0; ks < 8; ++ks) {                        \
      rw[2 * ks] = *(const float4*)(p_ + ks * 32);                            \
      rw[2 * ks + 1] = *(const float4*)(p_ + ks * 32 + 4);                    \
    } }

#define CVT(AF)                                                               \
  { _Pragma("unroll") for (int ks = 0; ks < 8; ++ks) {                        \
      AF[ks].u.x = pk2(rw[2 * ks].x, rw[2 * ks].y);                           \
      AF[ks].u.y = pk2(rw[2 * ks].z, rw[2 * ks].w);                           \
      AF[ks].u.z = pk2(rw[2 * ks + 1].x, rw[2 * ks + 1].y);                   \
      AF[ks].u.w = pk2(rw[2 * ks + 1].z, rw[2 * ks + 1].w);                   \
    } }

#define LOGITS(AF, DST)                                                       \
  { f32x4 d_ = {0.f, 0.f, 0.f, 0.f};                                          \
    _Pragma("unroll") for (int ks = 0; ks < 8; ++ks)                          \
      d_ = __builtin_amdgcn_mfma_f32_16x16x32_bf16(AF[ks].s, vfrag[ks], d_, 0, 0, 0); \
    DST = d_; }

  float m_run = -INFINITY, l_part = 0.f;
  f32x4 acc_s[16];
#pragma unroll
  for (int n = 0; n < 16; ++n) { f32x4 z = {0.f, 0.f, 0.f, 0.f}; acc_s[n] = z; }

  ISSUE(0);
  CVT(af0);
  ISSUE(1);

  for (int pp = 0; pp < 4; ++pp) {
    f32x4 l0, l1;
    LOGITS(af0, l0);
    CVT(af1);
    if (pp < 3) ISSUE(2 * pp + 2);
    LOGITS(af1, l1);

    // ---- online softmax over this 32-t pair (per head = dl) ----
    float tmax = fmaxf(fmaxf(fmaxf(l0.x, l0.y), fmaxf(l0.z, l0.w)),
                       fmaxf(fmaxf(l1.x, l1.y), fmaxf(l1.z, l1.w)));
    tmax = fmaxf(tmax, __shfl_xor(tmax, 16));
    tmax = fmaxf(tmax, __shfl_xor(tmax, 32));
    int need = (tmax > m_run + 8.f) && (dl < 8);
    if (__any(need)) {
      float mnew = fmaxf(m_run, tmax);
      float f = __expf(m_run - mnew);
      m_run = mnew;
      l_part *= f;
      float f0 = __shfl(f, kg * 4 + 0);
      float f1 = __shfl(f, kg * 4 + 1);
      float f2 = __shfl(f, kg * 4 + 2);
      float f3 = __shfl(f, kg * 4 + 3);
      if (kg < 2) {
#pragma unroll
        for (int n = 0; n < 16; ++n) {
          acc_s[n].x *= f0; acc_s[n].y *= f1; acc_s[n].z *= f2; acc_s[n].w *= f3;
        }
      }
    }
    float e00 = __expf(l0.x - m_run), e01 = __expf(l0.y - m_run);
    float e02 = __expf(l0.z - m_run), e03 = __expf(l0.w - m_run);
    float e10 = __expf(l1.x - m_run), e11 = __expf(l1.y - m_run);
    float e12 = __expf(l1.z - m_run), e13 = __expf(l1.w - m_run);
    l_part += (e00 + e01 + e02 + e03) + (e10 + e11 + e12 + e13);

    unsigned int pk00 = pk2(e00, e01), pk01 = pk2(e02, e03);
    unsigned int pk10 = pk2(e10, e11), pk11 = pk2(e12, e13);
    if (dl == 8) { pk00 = pk01 = pk10 = pk11 = 0x3F803F80u; } // ones row

    int sa = dl + ((kg & 1) ? 32 : 0);
    int sb = sa + 16;
    unsigned int g00 = __shfl(pk00, sa), g01 = __shfl(pk01, sa);
    unsigned int g02 = __shfl(pk00, sb), g03 = __shfl(pk01, sb);
    unsigned int g10 = __shfl(pk10, sa), g11 = __shfl(pk11, sa);
    unsigned int g12 = __shfl(pk10, sb), g13 = __shfl(pk11, sb);
    U8 eA;
    eA.u.x = (kg < 2) ? g00 : g10;
    eA.u.y = (kg < 2) ? g01 : g11;
    eA.u.z = (kg < 2) ? g02 : g12;
    eA.u.w = (kg < 2) ? g03 : g13;

    // ---- S += e^T @ fact (B from L2-hit transposed reads) ----
#pragma unroll
    for (int n = 0; n < 16; ++n) {
      float b0 = rpA[0 * DF_ + n * 16], b1 = rpA[1 * DF_ + n * 16];
      float b2 = rpA[2 * DF_ + n * 16], b3 = rpA[3 * DF_ + n * 16];
      float b4 = rpB[0 * DF_ + n * 16], b5 = rpB[1 * DF_ + n * 16];
      float b6 = rpB[2 * DF_ + n * 16], b7 = rpB[3 * DF_ + n * 16];
      U8 bb;
      bb.u.x = pk2(b0, b1); bb.u.y = pk2(b2, b3);
      bb.u.z = pk2(b4, b5); bb.u.w = pk2(b6, b7);
      acc_s[n] = __builtin_amdgcn_mfma_f32_16x16x32_bf16(eA.s, bb.s, acc_s[n], 0, 0, 0);
    }
    rpA += 32 * DF_; rpB += 32 * DF_;

    if (pp < 3) { CVT(af0); ISSUE(2 * pp + 3); }  // CVT hidden under scatter above
  }

  // ---- per-wave epilogue into LDS ----
  l_part += __shfl_xor(l_part, 16);
  l_part += __shfl_xor(l_part, 32);
  if (l < 8) { smML[w][0][l] = m_run; smML[w][1][l] = l_part; }
  if (kg < 2) {
#pragma unroll
    for (int n = 0; n < 16; ++n) {
      smS[w][kg * 4 + 0][n * 16 + dl] = acc_s[n].x;
      smS[w][kg * 4 + 1][n * 16 + dl] = acc_s[n].y;
      smS[w][kg * 4 + 2][n * 16 + dl] = acc_s[n].z;
      smS[w][kg * 4 + 3][n * 16 + dl] = acc_s[n].w;
    }
  } else if (kg == 2) {
#pragma unroll
    for (int n = 0; n < 16; ++n) smS[w][8][n * 16 + dl] = acc_s[n].x;
  }
  __syncthreads();

  // ---- merge the 4 waves -> one block partial ----
#pragma unroll
  for (int row = 0; row < 9; ++row) {
    float v = 0.f;
    if (row < 8) {
      float Mx = fmaxf(fmaxf(smML[0][0][row], smML[1][0][row]),
                       fmaxf(smML[2][0][row], smML[3][0][row]));
#pragma unroll
      for (int ww = 0; ww < 4; ++ww)
        v += __expf(smML[ww][0][row] - Mx) * smS[ww][row][tid];
    } else {
#pragma unroll
      for (int ww = 0; ww < 4; ++ww) v += smS[ww][8][tid];
    }
    part_s[(size_t)bid * PS_STRIDE + row * 256 + tid] = v;
  }
  if (tid < 8) {
    int h = tid;
    float Mx = fmaxf(fmaxf(smML[0][0][h], smML[1][0][h]),
                     fmaxf(smML[2][0][h], smML[3][0][h]));
    float Lc = 0.f;
#pragma unroll
    for (int ww = 0; ww < 4; ++ww)
      Lc += __expf(smML[ww][0][h] - Mx) * smML[ww][1][h];
    part_ml[(size_t)bid * 16 + h] = Mx;
    part_ml[(size_t)bid * 16 + 8 + h] = Lc;
  }
}

// combine 8 block-partials per (b,h); project through Wf[h]; add bias terms
__global__ __launch_bounds__(64) void reduce_k(const float* __restrict__ part_s,
    const float* __restrict__ part_ml, const float* __restrict__ Wf,
    const float* __restrict__ bf, float* __restrict__ out) {
  __shared__ float s_l[DF_];
  int bh = blockIdx.x, b = bh >> 3, h = bh & 7;
  int d = threadIdx.x;
  float M = -INFINITY;
  float mq[8];
#pragma unroll
  for (int q = 0; q < 8; ++q) {
    mq[q] = part_ml[(size_t)(b * 8 + q) * 16 + h];
    M = fmaxf(M, mq[q]);
  }
  float L = 0.f;
  float sa[4] = {0.f, 0.f, 0.f, 0.f}, cs[4] = {0.f, 0.f, 0.f, 0.f};
#pragma unroll
  for (int q = 0; q < 8; ++q) {
    float e = __expf(mq[q] - M);
    L += e * part_ml[(size_t)(b * 8 + q) * 16 + 8 + h];
    const float* ps = part_s + (size_t)(b * 8 + q) * PS_STRIDE;
#pragma unroll
    for (int c = 0; c < 4; ++c) {
      sa[c] += e * ps[h * 256 + c * 64 + d];
      cs[c] += ps[8 * 256 + c * 64 + d];
    }
  }
  float inv = 1.f / L;
#pragma unroll
  for (int c = 0; c < 4; ++c) s_l[c * 64 + d] = sa[c] * inv + EPS_ * cs[c];
  __syncthreads();
  const float* wcol = Wf + (size_t)h * DF_ * D_ + d;
  float o = 0.f;
#pragma unroll 8
  for (int k = 0; k < DF_; ++k) o += s_l[k] * wcol[(size_t)k * D_];
  o += (1.f + (float)T_ * EPS_) * bf[h * D_ + d];
  out[(size_t)b * (H_ * D_) + h * D_ + d] = o;
}

extern "C" void kernel_launch(void* const* d_in, const int* in_sizes, int n_in,
                              void* d_out, int out_size, void* d_ws, size_t ws_size,
                              hipStream_t stream) {
  const float* query = (const float*)d_in[0];
  const float* fact  = (const float*)d_in[1];
  const float* Wq    = (const float*)d_in[2];
  const float* bq    = (const float*)d_in[3];
  const float* Wf    = (const float*)d_in[4];
  const float* bf    = (const float*)d_in[5];
  float* out = (float*)d_out;

  char* ws = (char*)d_ws;
  float* fq = (float*)ws;                                  // 131072 B
  unsigned short* vB = (unsigned short*)(ws + 131072);     // 524288 B
  float* part_ml = (float*)(ws + 655360);                  // 32768 B
  float* part_s = (float*)(ws + 688128);                   // 4718592 B

  prep_fq<<<dim3(B_ * H_), dim3(256), 0, stream>>>(query, Wq, bq, fq);
  prep_v<<<dim3(B_ * H_), dim3(256), 0, stream>>>(Wf, fq, vB);
  mha_main<<<dim3(NBLK), dim3(256), 0, stream>>>(fact, vB, part_s, part_ml);
  reduce_k<<<dim3(B_ * H_), dim3(64), 0, stream>>>(part_s, part_ml, Wf, bf, out);
}

// Round 6
// 83.777 us; speedup vs baseline: 4.5445x; 1.6959x over previous
//
#include <hip/hip_runtime.h>
#include <hip/hip_bf16.h>

#define B_ 64
#define T_ 4096
#define DQ_ 512
#define DF_ 256
#define H_ 8
#define D_ 64
#define EPS_ 1e-7f
#define NBLK 512        /* (b, qq): 8 blocks per batch, 512 rows each */
#define CHUNK 32        /* rows per staged chunk */
#define NCH 16          /* chunks per block */
#define PS_STRIDE 2304  /* per-block partial: 9 rows x 256 */
#define ROWB 1040       /* padded LDS row bytes (260 dwords) */
#define SLOTS 2080      /* 32 rows x 65 16B-slots (slot 64 = pad) */
#define BUFB (SLOTS * 16)

typedef __attribute__((ext_vector_type(8))) short short8;
typedef __attribute__((ext_vector_type(4))) float f32x4;

union U8 { uint4 u; short8 s; };

#if defined(__has_builtin)
#if __has_builtin(__builtin_amdgcn_global_load_lds)
#define HAVE_GLL 1
#endif
#endif

#ifdef HAVE_GLL
static __device__ __forceinline__ void STAGE16(const void* g, void* l) {
  __builtin_amdgcn_global_load_lds(
      (const __attribute__((address_space(1))) unsigned int*)g,
      (__attribute__((address_space(3))) unsigned int*)l, 16, 0, 0);
}
#else
static __device__ __forceinline__ void STAGE16(const void* g, void* l) {
  *(float4*)l = *(const float4*)g;
}
#endif

static __device__ __forceinline__ unsigned int pk2(float a, float b) {
  __hip_bfloat162 h = __float22bfloat162_rn(make_float2(a, b));
  union { __hip_bfloat162 h; unsigned int u; } c; c.h = h;
  return c.u;
}

// fq[b,h,:] = q[b]@Wq[h] + bq[h]; 4-way f-split, LDS-staged q
__global__ __launch_bounds__(256) void prep_fq(const float* __restrict__ qin,
    const float* __restrict__ Wq, const float* __restrict__ bq,
    float* __restrict__ fq) {
  __shared__ float qs[DQ_];
  __shared__ float red[4][D_];
  int bh = blockIdx.x, b = bh >> 3, h = bh & 7;
  int tid = threadIdx.x, d = tid & 63, fc = tid >> 6;
  qs[tid] = qin[(size_t)b * DQ_ + tid];
  qs[tid + 256] = qin[(size_t)b * DQ_ + tid + 256];
  __syncthreads();
  const float* w = Wq + (size_t)h * DQ_ * D_ + (size_t)fc * 128 * D_ + d;
  float acc = 0.f;
#pragma unroll 8
  for (int i = 0; i < 128; ++i) acc += qs[fc * 128 + i] * w[(size_t)i * D_];
  red[fc][d] = acc;
  __syncthreads();
  if (fc == 0)
    fq[(size_t)bh * D_ + d] = acc + red[1][d] + red[2][d] + red[3][d] + bq[h * D_ + d];
}

// v[b,h,k] = Wf[h,k,:]·fq[b,h,:], packed bf16 B-fragments (zeros at dl=8+h)
__global__ __launch_bounds__(256) void prep_v(const float* __restrict__ Wf,
    const float* __restrict__ fq, unsigned short* __restrict__ vB) {
  __shared__ float fql[D_];
  int bh = blockIdx.x, b = bh >> 3, h = bh & 7;
  int k = threadIdx.x;
  if (k < D_) fql[k] = fq[(size_t)bh * D_ + k];
  __syncthreads();
  const float4* wr = (const float4*)(Wf + (size_t)h * DF_ * D_ + (size_t)k * D_);
  const float4* f4 = (const float4*)fql;
  float acc = 0.f;
#pragma unroll
  for (int i = 0; i < 16; ++i) {
    float4 wv = wr[i], fv = f4[i];
    acc += wv.x * fv.x + wv.y * fv.y + wv.z * fv.z + wv.w * fv.w;
  }
  int ks = k >> 5, kg = (k >> 3) & 3, j = k & 7;
  size_t base = (size_t)b * 4096 + ks * 512;
  vB[base + (kg * 16 + h) * 8 + j] = (unsigned short)(pk2(acc, 0.f) & 0xFFFF);
  vB[base + (kg * 16 + 8 + h) * 8 + j] = 0;
}

// Main: 512 blocks x 4 waves. Block owns 512 rows; fact DMA-staged (fp32,
// padded rows) double-buffered; waves split the 256 features 4x64.
// Logits: per-wave K=64 MFMA partial + LDS exchange. S: MFMA from LDS reads.
__global__ __launch_bounds__(256, 2) void mha_main(
    const float* __restrict__ fact, const unsigned short* __restrict__ vB,
    float* __restrict__ part_s, float* __restrict__ part_ml) {
  __shared__ char buf[2 * BUFB];        // 66560 B
  __shared__ float4 exch[2][4][64];     // 8192 B

  const int tid = threadIdx.x;
  const int l = tid & 63, w = tid >> 6;
  const int dl = l & 15, kg = l >> 4;
  const int bid = blockIdx.x;
  const int b = bid >> 3, qq = bid & 7;

  // this wave's 64-feature slice of the v B-fragments
  short8 vfrag[2];
#pragma unroll
  for (int ks = 0; ks < 2; ++ks)
    vfrag[ks] = *(const short8*)(vB + (size_t)b * 4096 + (2 * w + ks) * 512 + l * 8);

  const float* factb = fact + ((size_t)b * T_ + (size_t)qq * 512) * DF_;

  // staging map: id = i*256+tid -> (row, slot); slot 64 = pad (dummy src)
  int srow[9], sslot[9];
#pragma unroll
  for (int i = 0; i < 9; ++i) {
    int id = i * 256 + tid;
    srow[i] = id / 65;
    sslot[i] = id % 65;
  }

#define ISSUE(C) {                                                            \
    const char* gsrc = (const char*)(factb + (size_t)(C) * CHUNK * DF_);      \
    char* ldst = buf + ((C) & 1) * BUFB;                                      \
    _Pragma("unroll") for (int i = 0; i < 9; ++i) {                           \
      int id = i * 256 + tid;                                                 \
      if (i < 8 || id < SLOTS) {                                              \
        const void* sp = (sslot[i] < 64)                                      \
            ? (const void*)(gsrc + (size_t)srow[i] * 1024 + sslot[i] * 16)    \
            : (const void*)gsrc;                                              \
        STAGE16(sp, (void*)(ldst + id * 16));                                 \
      } } }

  float m_run = -INFINITY, l_part = 0.f;
  f32x4 acc_s[4];
#pragma unroll
  for (int n = 0; n < 4; ++n) { f32x4 z = {0.f, 0.f, 0.f, 0.f}; acc_s[n] = z; }

  ISSUE(0);

  for (int c = 0; c < NCH; ++c) {
    __syncthreads(); // buf[c&1] fully staged (drains outstanding DMA)
    if (c + 1 < NCH) ISSUE(c + 1);
    const char* bc = buf + (c & 1) * BUFB;

    // ---- part 1: per-tile A-fragments + K=64 logit partials ----
    f32x4 dp[2];
#pragma unroll
    for (int t2 = 0; t2 < 2; ++t2) {
      const char* arow = bc + (t2 * 16 + dl) * ROWB + (w * 64 + kg * 8) * 4;
      float4 a0 = *(const float4*)arow;
      float4 a1 = *(const float4*)(arow + 16);
      float4 a2 = *(const float4*)(arow + 128);
      float4 a3 = *(const float4*)(arow + 144);
      U8 af0, af1;
      af0.u.x = pk2(a0.x, a0.y); af0.u.y = pk2(a0.z, a0.w);
      af0.u.z = pk2(a1.x, a1.y); af0.u.w = pk2(a1.z, a1.w);
      af1.u.x = pk2(a2.x, a2.y); af1.u.y = pk2(a2.z, a2.w);
      af1.u.z = pk2(a3.x, a3.y); af1.u.w = pk2(a3.z, a3.w);
      f32x4 d_ = {0.f, 0.f, 0.f, 0.f};
      d_ = __builtin_amdgcn_mfma_f32_16x16x32_bf16(af0.s, vfrag[0], d_, 0, 0, 0);
      d_ = __builtin_amdgcn_mfma_f32_16x16x32_bf16(af1.s, vfrag[1], d_, 0, 0, 0);
      dp[t2] = d_;
      exch[t2][w][l] = make_float4(d_[0], d_[1], d_[2], d_[3]);
    }
    __syncthreads(); // exchange visible (also drains c+1 DMA; absorbed by 2 blk/CU)

    f32x4 l0 = dp[0], l1 = dp[1];
#pragma unroll
    for (int ww = 1; ww < 4; ++ww) {
      int o = (w + ww) & 3;
      float4 p0 = exch[0][o][l], p1 = exch[1][o][l];
      l0[0] += p0.x; l0[1] += p0.y; l0[2] += p0.z; l0[3] += p0.w;
      l1[0] += p1.x; l1[1] += p1.y; l1[2] += p1.z; l1[3] += p1.w;
    }

    // ---- online softmax (r4-verified): lane(dl=h) rows t = kg*4+r (+16 for l1)
    float tmax = fmaxf(fmaxf(fmaxf(l0[0], l0[1]), fmaxf(l0[2], l0[3])),
                       fmaxf(fmaxf(l1[0], l1[1]), fmaxf(l1[2], l1[3])));
    tmax = fmaxf(tmax, __shfl_xor(tmax, 16));
    tmax = fmaxf(tmax, __shfl_xor(tmax, 32));
    int need = (tmax > m_run + 8.f) && (dl < 8);
    if (__any(need)) {
      float mnew = fmaxf(m_run, tmax);
      float f = __expf(m_run - mnew);
      m_run = mnew;
      l_part *= f;
      float f0 = __shfl(f, kg * 4 + 0), f1 = __shfl(f, kg * 4 + 1);
      float f2 = __shfl(f, kg * 4 + 2), f3 = __shfl(f, kg * 4 + 3);
      if (kg < 2) {
#pragma unroll
        for (int n = 0; n < 4; ++n) {
          acc_s[n][0] *= f0; acc_s[n][1] *= f1; acc_s[n][2] *= f2; acc_s[n][3] *= f3;
        }
      }
    }
    float e0 = __expf(l0[0] - m_run), e1 = __expf(l0[1] - m_run);
    float e2 = __expf(l0[2] - m_run), e3 = __expf(l0[3] - m_run);
    float e4 = __expf(l1[0] - m_run), e5 = __expf(l1[1] - m_run);
    float e6 = __expf(l1[2] - m_run), e7 = __expf(l1[3] - m_run);
    l_part += (e0 + e1 + e2 + e3) + (e4 + e5 + e6 + e7);

    unsigned int pk00 = pk2(e0, e1), pk01 = pk2(e2, e3);
    unsigned int pk10 = pk2(e4, e5), pk11 = pk2(e6, e7);
    if (dl == 8) { pk00 = pk01 = pk10 = pk11 = 0x3F803F80u; } // ones row -> colsum

    int sa = dl + ((kg & 1) ? 32 : 0);
    int sb = sa + 16;
    unsigned int g00 = __shfl(pk00, sa), g01 = __shfl(pk01, sa);
    unsigned int g02 = __shfl(pk00, sb), g03 = __shfl(pk01, sb);
    unsigned int g10 = __shfl(pk10, sa), g11 = __shfl(pk11, sa);
    unsigned int g12 = __shfl(pk10, sb), g13 = __shfl(pk11, sb);
    U8 eA;
    eA.u.x = (kg < 2) ? g00 : g10;
    eA.u.y = (kg < 2) ? g01 : g11;
    eA.u.z = (kg < 2) ? g02 : g12;
    eA.u.w = (kg < 2) ? g03 : g13;

    // ---- S += e^T @ chunk, B-fragments from LDS (wave's 64-f slice) ----
#pragma unroll
    for (int n = 0; n < 4; ++n) {
      const char* srd = bc + (w * 64 + n * 16 + dl) * 4;
      float b0 = *(const float*)(srd + (kg * 8 + 0) * ROWB);
      float b1 = *(const float*)(srd + (kg * 8 + 1) * ROWB);
      float b2 = *(const float*)(srd + (kg * 8 + 2) * ROWB);
      float b3 = *(const float*)(srd + (kg * 8 + 3) * ROWB);
      float b4 = *(const float*)(srd + (kg * 8 + 4) * ROWB);
      float b5 = *(const float*)(srd + (kg * 8 + 5) * ROWB);
      float b6 = *(const float*)(srd + (kg * 8 + 6) * ROWB);
      float b7 = *(const float*)(srd + (kg * 8 + 7) * ROWB);
      U8 bb;
      bb.u.x = pk2(b0, b1); bb.u.y = pk2(b2, b3);
      bb.u.z = pk2(b4, b5); bb.u.w = pk2(b6, b7);
      acc_s[n] = __builtin_amdgcn_mfma_f32_16x16x32_bf16(eA.s, bb.s, acc_s[n], 0, 0, 0);
    }
  }

  // ---- epilogue ----
  l_part += __shfl_xor(l_part, 16);
  l_part += __shfl_xor(l_part, 32);
  if (w == 0 && l < 8) {
    part_ml[(size_t)bid * 16 + l] = m_run;
    part_ml[(size_t)bid * 16 + 8 + l] = l_part;
  }
  float* ps = part_s + (size_t)bid * PS_STRIDE;
  if (kg < 2) {
#pragma unroll
    for (int n = 0; n < 4; ++n) {
      int f = w * 64 + n * 16 + dl;
      ps[(kg * 4 + 0) * 256 + f] = acc_s[n][0];
      ps[(kg * 4 + 1) * 256 + f] = acc_s[n][1];
      ps[(kg * 4 + 2) * 256 + f] = acc_s[n][2];
      ps[(kg * 4 + 3) * 256 + f] = acc_s[n][3];
    }
  } else if (kg == 2) {
#pragma unroll
    for (int n = 0; n < 4; ++n)
      ps[8 * 256 + w * 64 + n * 16 + dl] = acc_s[n][0]; // colsum row
  }
}

// combine 8 block-partials per (b,h); project through Wf[h]; add bias terms
__global__ __launch_bounds__(64) void reduce_k(const float* __restrict__ part_s,
    const float* __restrict__ part_ml, const float* __restrict__ Wf,
    const float* __restrict__ bf, float* __restrict__ out) {
  __shared__ float s_l[DF_];
  int bh = blockIdx.x, b = bh >> 3, h = bh & 7;
  int d = threadIdx.x;
  float M = -INFINITY;
  float mq[8];
#pragma unroll
  for (int q = 0; q < 8; ++q) {
    mq[q] = part_ml[(size_t)(b * 8 + q) * 16 + h];
    M = fmaxf(M, mq[q]);
  }
  float L = 0.f;
  float sa[4] = {0.f, 0.f, 0.f, 0.f}, cs[4] = {0.f, 0.f, 0.f, 0.f};
#pragma unroll
  for (int q = 0; q < 8; ++q) {
    float e = __expf(mq[q] - M);
    L += e * part_ml[(size_t)(b * 8 + q) * 16 + 8 + h];
    const float* ps = part_s + (size_t)(b * 8 + q) * PS_STRIDE;
#pragma unroll
    for (int c = 0; c < 4; ++c) {
      sa[c] += e * ps[h * 256 + c * 64 + d];
      cs[c] += ps[8 * 256 + c * 64 + d];
    }
  }
  float inv = 1.f / L;
#pragma unroll
  for (int c = 0; c < 4; ++c) s_l[c * 64 + d] = sa[c] * inv + EPS_ * cs[c];
  __syncthreads();
  const float* wcol = Wf + (size_t)h * DF_ * D_ + d;
  float o = 0.f;
#pragma unroll 8
  for (int k = 0; k < DF_; ++k) o += s_l[k] * wcol[(size_t)k * D_];
  o += (1.f + (float)T_ * EPS_) * bf[h * D_ + d];
  out[(size_t)b * (H_ * D_) + h * D_ + d] = o;
}

extern "C" void kernel_launch(void* const* d_in, const int* in_sizes, int n_in,
                              void* d_out, int out_size, void* d_ws, size_t ws_size,
                              hipStream_t stream) {
  const float* query = (const float*)d_in[0];
  const float* fact  = (const float*)d_in[1];
  const float* Wq    = (const float*)d_in[2];
  const float* bq    = (const float*)d_in[3];
  const float* Wf    = (const float*)d_in[4];
  const float* bf    = (const float*)d_in[5];
  float* out = (float*)d_out;

  char* ws = (char*)d_ws;
  float* fq = (float*)ws;                                  // 131072 B
  unsigned short* vB = (unsigned short*)(ws + 131072);     // 524288 B
  float* part_ml = (float*)(ws + 655360);                  // 32768 B
  float* part_s = (float*)(ws + 688128);                   // 4718592 B

  prep_fq<<<dim3(B_ * H_), dim3(256), 0, stream>>>(query, Wq, bq, fq);
  prep_v<<<dim3(B_ * H_), dim3(256), 0, stream>>>(Wf, fq, vB);
  mha_main<<<dim3(NBLK), dim3(256), 0, stream>>>(fact, vB, part_s, part_ml);
  reduce_k<<<dim3(B_ * H_), dim3(64), 0, stream>>>(part_s, part_ml, Wf, bf, out);
}

// Round 7
// 69.197 us; speedup vs baseline: 5.5020x; 1.2107x over previous
//
#include <hip/hip_runtime.h>
#include <hip/hip_bf16.h>

#define B_ 64
#define T_ 4096
#define DQ_ 512
#define DF_ 256
#define H_ 8
#define D_ 64
#define EPS_ 1e-7f
#define NBLK 512        /* (b, qq): 8 blocks per batch, 512 rows each */
#define CHUNK 32        /* rows per staged chunk */
#define NCH 16          /* chunks per block */
#define PS_STRIDE 2304  /* per-block partial: 9 rows x 256 */
#define ROWB 1040       /* padded LDS row bytes (260 dwords, 65 16B slots) */
#define SLOTS 2080      /* 32 rows x 65 slots (slot 64 = pad) */
#define BUFB (SLOTS * 16)

typedef __attribute__((ext_vector_type(8))) short short8;
typedef __attribute__((ext_vector_type(4))) float f32x4;

union U8 { uint4 u; short8 s; };

#if defined(__has_builtin)
#if __has_builtin(__builtin_amdgcn_global_load_lds)
#define HAVE_GLL 1
#endif
#endif

#ifdef HAVE_GLL
static __device__ __forceinline__ void STAGE16(const void* g, void* l) {
  __builtin_amdgcn_global_load_lds(
      (const __attribute__((address_space(1))) unsigned int*)g,
      (__attribute__((address_space(3))) unsigned int*)l, 16, 0, 0);
}
#else
static __device__ __forceinline__ void STAGE16(const void* g, void* l) {
  *(float4*)l = *(const float4*)g;
}
#endif

static __device__ __forceinline__ unsigned int pk2(float a, float b) {
  __hip_bfloat162 h = __float22bfloat162_rn(make_float2(a, b));
  union { __hip_bfloat162 h; unsigned int u; } c; c.h = h;
  return c.u;
}

// merged prep: fq[b,h,:] = q[b]@Wq[h]+bq[h] (kept in LDS), then
// v[b,h,k] = Wf[h,k,:]·fq, packed bf16 B-fragments (zeros at dl=8+h)
__global__ __launch_bounds__(256) void prep(const float* __restrict__ qin,
    const float* __restrict__ Wq, const float* __restrict__ bq,
    const float* __restrict__ Wf, unsigned short* __restrict__ vB) {
  __shared__ float qs[DQ_];
  __shared__ float red[4][D_];
  __shared__ float fql[D_];
  int bh = blockIdx.x, b = bh >> 3, h = bh & 7;
  int tid = threadIdx.x, d = tid & 63, fc = tid >> 6;
  qs[tid] = qin[(size_t)b * DQ_ + tid];
  qs[tid + 256] = qin[(size_t)b * DQ_ + tid + 256];
  __syncthreads();
  {
    const float* w = Wq + (size_t)h * DQ_ * D_ + (size_t)fc * 128 * D_ + d;
    float acc = 0.f;
#pragma unroll 8
    for (int i = 0; i < 128; ++i) acc += qs[fc * 128 + i] * w[(size_t)i * D_];
    red[fc][d] = acc;
  }
  __syncthreads();
  if (fc == 0)
    fql[d] = red[0][d] + red[1][d] + red[2][d] + red[3][d] + bq[h * D_ + d];
  __syncthreads();
  // v phase: k = tid (256 rows of Wf[h])
  const float4* wr = (const float4*)(Wf + (size_t)h * DF_ * D_ + (size_t)tid * D_);
  const float4* f4 = (const float4*)fql;
  float acc = 0.f;
#pragma unroll
  for (int i = 0; i < 16; ++i) {
    float4 wv = wr[i], fv = f4[i];
    acc += wv.x * fv.x + wv.y * fv.y + wv.z * fv.z + wv.w * fv.w;
  }
  int ks = tid >> 5, kg = (tid >> 3) & 3, j = tid & 7;
  size_t base = (size_t)b * 4096 + ks * 512;
  vB[base + (kg * 16 + h) * 8 + j] = (unsigned short)(pk2(acc, 0.f) & 0xFFFF);
  vB[base + (kg * 16 + 8 + h) * 8 + j] = 0;
}

// Main: 512 blocks x 4 waves. fact DMA-staged (fp32, padded+row-permuted rows)
// double-buffered; waves split 256 features 4x64. ISSUE placed after barrier-2
// so the whole softmax+S phase covers the DMA; row-permute π kills the S-phase
// 4-way bank conflict (source-side inverse perm, read-side perm).
__global__ __launch_bounds__(256, 2) void mha_main(
    const float* __restrict__ fact, const unsigned short* __restrict__ vB,
    float* __restrict__ part_s, float* __restrict__ part_ml) {
  __shared__ char buf[2 * BUFB];        // 66560 B
  __shared__ float4 exch[2][4][64];     // 8192 B

  const int tid = threadIdx.x;
  const int l = tid & 63, w = tid >> 6;
  const int dl = l & 15, kg = l >> 4;
  const int bid = blockIdx.x;
  const int b = bid >> 3, qq = bid & 7;

  // this wave's 64-feature slice of the v B-fragments
  short8 vfrag[2];
#pragma unroll
  for (int ks = 0; ks < 2; ++ks)
    vfrag[ks] = *(const short8*)(vB + (size_t)b * 4096 + (2 * w + ks) * 512 + l * 8);

  const float* factb = fact + ((size_t)b * T_ + (size_t)qq * 512) * DF_;

  // staging map: LDS granule id -> (LDS row rho, slot); global row = pi^-1(rho)
  int srow[9], sslot[9];
#pragma unroll
  for (int i = 0; i < 9; ++i) {
    int id = i * 256 + tid;
    int rho = id / 65;
    int kgr = (rho >> 3) & 3;
    srow[i] = (rho & ~7) | (((rho & 7) + 8 - 2 * kgr) & 7);
    sslot[i] = id % 65;
  }

  // A-side LDS rows for lane's tiles (pi applied)
  const int t0 = dl, t1 = 16 + dl;
  const int lr0 = (t0 & ~7) | (((t0 & 7) + 2 * ((t0 >> 3) & 3)) & 7);
  const int lr1 = (t1 & ~7) | (((t1 & 7) + 2 * ((t1 >> 3) & 3)) & 7);
  const int aoff0 = lr0 * ROWB + (w * 64 + kg * 8) * 4;
  const int aoff1 = lr1 * ROWB + (w * 64 + kg * 8) * 4;
  // S-side LDS row byte offsets for k-rows kg*8+j (pi applied)
  int roff[8];
#pragma unroll
  for (int j = 0; j < 8; ++j)
    roff[j] = (kg * 8 + ((j + 2 * kg) & 7)) * ROWB;

#define ISSUE(C) {                                                            \
    const char* gsrc = (const char*)(factb + (size_t)(C) * CHUNK * DF_);      \
    char* ldst = buf + ((C) & 1) * BUFB;                                      \
    _Pragma("unroll") for (int i = 0; i < 9; ++i) {                           \
      int id = i * 256 + tid;                                                 \
      if (i < 8 || id < SLOTS) {                                              \
        const void* sp = (sslot[i] < 64)                                      \
            ? (const void*)(gsrc + (size_t)srow[i] * 1024 + sslot[i] * 16)    \
            : (const void*)gsrc;                                              \
        STAGE16(sp, (void*)(ldst + id * 16));                                 \
      } } }

  float m_run = -INFINITY, l_part = 0.f;
  f32x4 acc_s[4];
#pragma unroll
  for (int n = 0; n < 4; ++n) { f32x4 z = {0.f, 0.f, 0.f, 0.f}; acc_s[n] = z; }

  ISSUE(0);

  for (int c = 0; c < NCH; ++c) {
    __syncthreads(); // chunk c DMA drained; exch from c-1 fully consumed
    const char* bc = buf + (c & 1) * BUFB;

    // ---- part 1: per-tile A-fragments + K=64 logit partials ----
    f32x4 dp[2];
#pragma unroll
    for (int t2 = 0; t2 < 2; ++t2) {
      const char* arow = bc + (t2 ? aoff1 : aoff0);
      float4 a0 = *(const float4*)arow;
      float4 a1 = *(const float4*)(arow + 16);
      float4 a2 = *(const float4*)(arow + 128);
      float4 a3 = *(const float4*)(arow + 144);
      U8 af0, af1;
      af0.u.x = pk2(a0.x, a0.y); af0.u.y = pk2(a0.z, a0.w);
      af0.u.z = pk2(a1.x, a1.y); af0.u.w = pk2(a1.z, a1.w);
      af1.u.x = pk2(a2.x, a2.y); af1.u.y = pk2(a2.z, a2.w);
      af1.u.z = pk2(a3.x, a3.y); af1.u.w = pk2(a3.z, a3.w);
      f32x4 d_ = {0.f, 0.f, 0.f, 0.f};
      d_ = __builtin_amdgcn_mfma_f32_16x16x32_bf16(af0.s, vfrag[0], d_, 0, 0, 0);
      d_ = __builtin_amdgcn_mfma_f32_16x16x32_bf16(af1.s, vfrag[1], d_, 0, 0, 0);
      dp[t2] = d_;
      exch[t2][w][l] = make_float4(d_[0], d_[1], d_[2], d_[3]);
    }
    __syncthreads(); // exch visible (no vmem outstanding here)

    if (c + 1 < NCH) ISSUE(c + 1); // covered by softmax + S-phase below

    f32x4 l0 = dp[0], l1 = dp[1];
#pragma unroll
    for (int ww = 1; ww < 4; ++ww) {
      int o = (w + ww) & 3;
      float4 p0 = exch[0][o][l], p1 = exch[1][o][l];
      l0[0] += p0.x; l0[1] += p0.y; l0[2] += p0.z; l0[3] += p0.w;
      l1[0] += p1.x; l1[1] += p1.y; l1[2] += p1.z; l1[3] += p1.w;
    }

    // ---- online softmax: lane(dl=h) rows t = kg*4+r (+16 for l1) ----
    float tmax = fmaxf(fmaxf(fmaxf(l0[0], l0[1]), fmaxf(l0[2], l0[3])),
                       fmaxf(fmaxf(l1[0], l1[1]), fmaxf(l1[2], l1[3])));
    tmax = fmaxf(tmax, __shfl_xor(tmax, 16));
    tmax = fmaxf(tmax, __shfl_xor(tmax, 32));
    int need = (tmax > m_run + 8.f) && (dl < 8);
    if (__any(need)) {
      float mnew = fmaxf(m_run, tmax);
      float f = __expf(m_run - mnew);
      m_run = mnew;
      l_part *= f;
      float f0 = __shfl(f, kg * 4 + 0), f1 = __shfl(f, kg * 4 + 1);
      float f2 = __shfl(f, kg * 4 + 2), f3 = __shfl(f, kg * 4 + 3);
      if (kg < 2) {
#pragma unroll
        for (int n = 0; n < 4; ++n) {
          acc_s[n][0] *= f0; acc_s[n][1] *= f1; acc_s[n][2] *= f2; acc_s[n][3] *= f3;
        }
      }
    }
    float e0 = __expf(l0[0] - m_run), e1 = __expf(l0[1] - m_run);
    float e2 = __expf(l0[2] - m_run), e3 = __expf(l0[3] - m_run);
    float e4 = __expf(l1[0] - m_run), e5 = __expf(l1[1] - m_run);
    float e6 = __expf(l1[2] - m_run), e7 = __expf(l1[3] - m_run);
    l_part += (e0 + e1 + e2 + e3) + (e4 + e5 + e6 + e7);

    unsigned int pk00 = pk2(e0, e1), pk01 = pk2(e2, e3);
    unsigned int pk10 = pk2(e4, e5), pk11 = pk2(e6, e7);
    if (dl == 8) { pk00 = pk01 = pk10 = pk11 = 0x3F803F80u; } // ones -> colsum

    int sa = dl + ((kg & 1) ? 32 : 0);
    int sb = sa + 16;
    unsigned int g00 = __shfl(pk00, sa), g01 = __shfl(pk01, sa);
    unsigned int g02 = __shfl(pk00, sb), g03 = __shfl(pk01, sb);
    unsigned int g10 = __shfl(pk10, sa), g11 = __shfl(pk11, sa);
    unsigned int g12 = __shfl(pk10, sb), g13 = __shfl(pk11, sb);
    U8 eA;
    eA.u.x = (kg < 2) ? g00 : g10;
    eA.u.y = (kg < 2) ? g01 : g11;
    eA.u.z = (kg < 2) ? g02 : g12;
    eA.u.w = (kg < 2) ? g03 : g13;

    // ---- S += e^T @ chunk; B-fragments via permuted column walk (2-way) ----
#pragma unroll
    for (int n = 0; n < 4; ++n) {
      const char* srd = bc + (size_t)(w * 64 + n * 16 + dl) * 4;
      float b0 = *(const float*)(srd + roff[0]);
      float b1 = *(const float*)(srd + roff[1]);
      float b2 = *(const float*)(srd + roff[2]);
      float b3 = *(const float*)(srd + roff[3]);
      float b4 = *(const float*)(srd + roff[4]);
      float b5 = *(const float*)(srd + roff[5]);
      float b6 = *(const float*)(srd + roff[6]);
      float b7 = *(const float*)(srd + roff[7]);
      U8 bb;
      bb.u.x = pk2(b0, b1); bb.u.y = pk2(b2, b3);
      bb.u.z = pk2(b4, b5); bb.u.w = pk2(b6, b7);
      acc_s[n] = __builtin_amdgcn_mfma_f32_16x16x32_bf16(eA.s, bb.s, acc_s[n], 0, 0, 0);
    }
  }

  // ---- epilogue ----
  l_part += __shfl_xor(l_part, 16);
  l_part += __shfl_xor(l_part, 32);
  if (w == 0 && l < 8) {
    part_ml[(size_t)bid * 16 + l] = m_run;
    part_ml[(size_t)bid * 16 + 8 + l] = l_part;
  }
  float* ps = part_s + (size_t)bid * PS_STRIDE;
  if (kg < 2) {
#pragma unroll
    for (int n = 0; n < 4; ++n) {
      int f = w * 64 + n * 16 + dl;
      ps[(kg * 4 + 0) * 256 + f] = acc_s[n][0];
      ps[(kg * 4 + 1) * 256 + f] = acc_s[n][1];
      ps[(kg * 4 + 2) * 256 + f] = acc_s[n][2];
      ps[(kg * 4 + 3) * 256 + f] = acc_s[n][3];
    }
  } else if (kg == 2) {
#pragma unroll
    for (int n = 0; n < 4; ++n)
      ps[8 * 256 + w * 64 + n * 16 + dl] = acc_s[n][0]; // colsum row
  }
}

// combine 8 block-partials per (b,h); project through Wf[h]; add bias terms
__global__ __launch_bounds__(256) void reduce_k(const float* __restrict__ part_s,
    const float* __restrict__ part_ml, const float* __restrict__ Wf,
    const float* __restrict__ bf, float* __restrict__ out) {
  __shared__ float s_l[DF_];
  __shared__ float red[4][D_];
  int bh = blockIdx.x, b = bh >> 3, h = bh & 7;
  int tid = threadIdx.x, d = tid & 63, fc = tid >> 6;
  float M = -INFINITY;
  float mq[8];
#pragma unroll
  for (int q = 0; q < 8; ++q) {
    mq[q] = part_ml[(size_t)(b * 8 + q) * 16 + h];
    M = fmaxf(M, mq[q]);
  }
  float L = 0.f, sa = 0.f, cs = 0.f;
#pragma unroll
  for (int q = 0; q < 8; ++q) {
    float e = __expf(mq[q] - M);
    L += e * part_ml[(size_t)(b * 8 + q) * 16 + 8 + h];
    const float* ps = part_s + (size_t)(b * 8 + q) * PS_STRIDE;
    sa += e * ps[h * 256 + tid];
    cs += ps[8 * 256 + tid];
  }
  s_l[tid] = sa / L + EPS_ * cs;
  __syncthreads();
  const float* wbase = Wf + (size_t)h * DF_ * D_ + (size_t)fc * 64 * D_ + d;
  float o = 0.f;
#pragma unroll 8
  for (int k = 0; k < 64; ++k) o += s_l[fc * 64 + k] * wbase[(size_t)k * D_];
  red[fc][d] = o;
  __syncthreads();
  if (fc == 0)
    out[(size_t)b * (H_ * D_) + h * D_ + d] =
        o + red[1][d] + red[2][d] + red[3][d] + (1.f + (float)T_ * EPS_) * bf[h * D_ + d];
}

extern "C" void kernel_launch(void* const* d_in, const int* in_sizes, int n_in,
                              void* d_out, int out_size, void* d_ws, size_t ws_size,
                              hipStream_t stream) {
  const float* query = (const float*)d_in[0];
  const float* fact  = (const float*)d_in[1];
  const float* Wq    = (const float*)d_in[2];
  const float* bq    = (const float*)d_in[3];
  const float* Wf    = (const float*)d_in[4];
  const float* bf    = (const float*)d_in[5];
  float* out = (float*)d_out;

  char* ws = (char*)d_ws;
  unsigned short* vB = (unsigned short*)ws;                // 524288 B
  float* part_ml = (float*)(ws + 524288);                  // 32768 B
  float* part_s = (float*)(ws + 557056);                   // 4718592 B

  prep<<<dim3(B_ * H_), dim3(256), 0, stream>>>(query, Wq, bq, Wf, vB);
  mha_main<<<dim3(NBLK), dim3(256), 0, stream>>>(fact, vB, part_s, part_ml);
  reduce_k<<<dim3(B_ * H_), dim3(256), 0, stream>>>(part_s, part_ml, Wf, bf, out);
}